// Round 2
// baseline (232.960 us; speedup 1.0000x reference)
//
#include <hip/hip_runtime.h>

// Problem constants
#define G_GRAPHS 1024
#define N_NODES  40
#define M_EDGES  780          // N*(N-1)/2
#define NUM_NODES (G_GRAPHS * N_NODES)          // 40960
#define H_ELEMS  (NUM_NODES * 64)               // 2621440
#define X_STRIDE 160
#define X_PER_G  25600
#define SLOPE 0.1f

#define PACK_PER_MLP 9216     // W0(4096) + W1(4096) + W2(1024) bf16 elems

typedef __bf16 bf16x8 __attribute__((ext_vector_type(8)));
typedef unsigned short us8 __attribute__((ext_vector_type(8)));
typedef float f32x4 __attribute__((ext_vector_type(4)));

__device__ __forceinline__ float lrelu(float v) { return fmaxf(v, SLOPE * v); }
__device__ __forceinline__ unsigned short f2bf(float x) {
    __bf16 b = (__bf16)x;                       // RNE convert
    return __builtin_bit_cast(unsigned short, b);
}
__device__ __forceinline__ unsigned int pk2bf(float a, float b) {
    return (unsigned int)f2bf(a) | ((unsigned int)f2bf(b) << 16);
}

// ---------------------------------------------------------------------------
// K0: pack MLP weights (bf16) in d_ws. Layout serves the A-frag role:
// element for lane l, reg j, tile (mt,kt) of W^T is
// W[kt*32 + ((l>>4)&3)*8 + j][mt*16 + (l&15)]  -> linear ((mt*2+kt)*64+l)*8+j.
// W2 padded 10->16 cols (zeros). [0..9215] edge MLP, [9216..18431] node MLP.
// ---------------------------------------------------------------------------
__global__ __launch_bounds__(256) void k_prep(const float* __restrict__ We0,
                                              const float* __restrict__ We1,
                                              const float* __restrict__ We2,
                                              const float* __restrict__ Wn0,
                                              const float* __restrict__ Wn1,
                                              const float* __restrict__ Wn2,
                                              unsigned short* __restrict__ wp) {
    int t = blockIdx.x * 256 + threadIdx.x;     // 0..18431 (72 blocks)
    int mlp = t / PACK_PER_MLP;
    int o = t - mlp * PACK_PER_MLP;
    const float* W0 = mlp ? Wn0 : We0;
    const float* W1 = mlp ? Wn1 : We1;
    const float* W2 = mlp ? Wn2 : We2;
    float val;
    if (o < 8192) {
        const float* W = (o < 4096) ? W0 : W1;
        int idx = o & 4095;
        int j = idx & 7, l = (idx >> 3) & 63, tt = idx >> 9;   // tt = mt*2+kt
        int kt = tt & 1, mt = tt >> 1;
        int k = kt * 32 + ((l >> 4) & 3) * 8 + j;
        int m = mt * 16 + (l & 15);
        val = W[k * 64 + m];
    } else {
        int idx = o - 8192;                      // 0..1023, mt=0 only
        int j = idx & 7, l = (idx >> 3) & 63, kt = idx >> 9;
        int k = kt * 32 + ((l >> 4) & 3) * 8 + j;
        int m = l & 15;
        val = (m < 10) ? W2[k * 10 + m] : 0.f;
    }
    wp[mlp * PACK_PER_MLP + o] = f2bf(val);
}

// ---------------------------------------------------------------------------
// K1: 3-layer GCN, one block per graph (unchanged from round 1).
// ---------------------------------------------------------------------------
__global__ __launch_bounds__(256, 4) void k_gcn(const float* __restrict__ x,
                                                const float* __restrict__ Wg0,
                                                const float* __restrict__ bg0,
                                                const float* __restrict__ Wg1,
                                                const float* __restrict__ bg1,
                                                const float* __restrict__ Wg2,
                                                const float* __restrict__ bg2,
                                                float* __restrict__ hout) {
    __shared__ __align__(16) float h0[N_NODES * 6];
    __shared__ __align__(16) float buf[N_NODES * 64];
    __shared__ float S[64];
    __shared__ float P[8 * 64];
    __shared__ __align__(16) float h1[N_NODES * 32];
    __shared__ __align__(16) float h2[N_NODES * 32];

    const int g = blockIdx.x;
    const int tid = threadIdx.x;
    const float inv39 = 1.0f / 39.0f;
    const int c32 = tid & 31;
    const int c64 = tid & 63;

    float w0c[6], w1c[32], w2c[32];
#pragma unroll
    for (int f = 0; f < 6; f++)  w0c[f] = Wg0[f * 32 + c32];
#pragma unroll
    for (int m = 0; m < 32; m++) w1c[m] = Wg1[m * 32 + c32];
#pragma unroll
    for (int m = 0; m < 32; m++) w2c[m] = Wg2[m * 64 + c64];
    const float b0c = bg0[c32];
    const float b1c = bg1[c32];
    const float b2c = bg2[c64];

    for (int idx = tid; idx < N_NODES * 6; idx += 256) {
        int n = idx / 6, f = idx - n * 6;
        h0[idx] = x[(g * N_NODES + n) * 16 + f];
    }
    __syncthreads();

    // ---- layer 0 ----
    {
        int n0 = tid >> 5;
#pragma unroll
        for (int t = 0; t < 5; t++) {
            int n = n0 + 8 * t;
            float s = 0.f;
#pragma unroll
            for (int f = 0; f < 6; f++) s += h0[n * 6 + f] * w0c[f];
            buf[n * 32 + c32] = s;
        }
    }
    __syncthreads();
    { int grp = tid >> 5; float s = 0.f;
#pragma unroll
      for (int n = grp * 5; n < grp * 5 + 5; n++) s += buf[n * 32 + c32];
      P[grp * 32 + c32] = s; }
    __syncthreads();
    if (tid < 32) { float s = 0.f;
#pragma unroll
      for (int grp = 0; grp < 8; grp++) s += P[grp * 32 + tid];
      S[tid] = s; }
    __syncthreads();
    for (int idx = tid; idx < N_NODES * 32; idx += 256)
        h1[idx] = lrelu((S[c32] - buf[idx]) * inv39 + b0c);
    __syncthreads();

    // ---- layer 1 ----
    {
        int n0 = tid >> 5;
#pragma unroll
        for (int t = 0; t < 5; t++) {
            int n = n0 + 8 * t;
            const float4* hp = (const float4*)(h1 + n * 32);
            float s = 0.f;
#pragma unroll
            for (int q = 0; q < 8; q++) {
                float4 hv = hp[q];
                s += hv.x * w1c[4 * q + 0] + hv.y * w1c[4 * q + 1]
                   + hv.z * w1c[4 * q + 2] + hv.w * w1c[4 * q + 3];
            }
            buf[n * 32 + c32] = s;
        }
    }
    __syncthreads();
    { int grp = tid >> 5; float s = 0.f;
#pragma unroll
      for (int n = grp * 5; n < grp * 5 + 5; n++) s += buf[n * 32 + c32];
      P[grp * 32 + c32] = s; }
    __syncthreads();
    if (tid < 32) { float s = 0.f;
#pragma unroll
      for (int grp = 0; grp < 8; grp++) s += P[grp * 32 + tid];
      S[tid] = s; }
    __syncthreads();
    for (int idx = tid; idx < N_NODES * 32; idx += 256)
        h2[idx] = lrelu((S[c32] - buf[idx]) * inv39 + b1c);
    __syncthreads();

    // ---- layer 2 ----
    {
        int n0 = tid >> 6;
#pragma unroll
        for (int t = 0; t < 10; t++) {
            int n = n0 + 4 * t;
            const float4* hp = (const float4*)(h2 + n * 32);
            float s = 0.f;
#pragma unroll
            for (int q = 0; q < 8; q++) {
                float4 hv = hp[q];
                s += hv.x * w2c[4 * q + 0] + hv.y * w2c[4 * q + 1]
                   + hv.z * w2c[4 * q + 2] + hv.w * w2c[4 * q + 3];
            }
            buf[n * 64 + c64] = s;
        }
    }
    __syncthreads();
    { int grp = tid >> 6; float s = 0.f;
#pragma unroll
      for (int n = grp * 10; n < grp * 10 + 10; n++) s += buf[n * 64 + c64];
      P[grp * 64 + c64] = s; }
    __syncthreads();
    if (tid < 64) { float s = 0.f;
#pragma unroll
      for (int grp = 0; grp < 4; grp++) s += P[grp * 64 + tid];
      S[tid] = s; }
    __syncthreads();
    for (int idx = tid; idx < N_NODES * 64; idx += 256)
        hout[g * N_NODES * 64 + idx] = (S[c64] - buf[idx]) * inv39 + b2c;
}

// ---------------------------------------------------------------------------
// K2 v4: ONE GRAPH PER BLOCK.
//  - h (40x64 f32, 10.25 KB) loaded once, coalesced, XOR-swizzled into LDS
//    (us = u ^ ((row&7)<<1) on 16B units: consecutive-row float4 reads hit
//    distinct banks; without it pb-reads are a 16-way conflict).
//  - 820 MLP rows (780 edge + 40 node) padded to 27 wave-local 32-row chunks
//    (chunks 0..24 edge rows incl. 20 dummies, 25..26 node rows). Same
//    verified MFMA machinery; edge weights+biases hoisted to registers
//    (chunk-invariant); node set loaded only for its 2 chunks.
//  - EP (820 x 10 f32, stride 10, 32.8 KB) stays in LDS.
//  - X written by a coalesced sweep: thread owns whole 4x4 blocks, reads the
//    EP row (5x b64 LDS), assembles r0..r3, stores to consecutive addresses.
//  LDS total 59,424 B -> 2 blocks/CU (occupancy drops by design: round-1
//  proved waves aren't the lever; divergent-transaction count is).
// ---------------------------------------------------------------------------
struct ChunkRegs {
    bf16x8 A1[4][2];
    bf16x8 A2[4][2];
    bf16x8 A3[2];
    float4 bv0[4];
    float4 bv1[4];
    float  bz[4];
};

__device__ __forceinline__ void run_chunk(int R0, int w, int l,
                                          const float4* sh4,
                                          unsigned short* sB,
                                          float* sEP,
                                          const ChunkRegs& cr) {
    const int nl = l & 15;
    const int rq = (l >> 4) & 3;

    // ---- E build: row R0+rl, features [hf*32, hf*32+32) -> sB (swizzled) ----
    {
        int rl = l >> 1, hf2 = l & 1;
        int row = R0 + rl;
        int ii = 0, jj = 0;
        bool addf = false;
        if (row < 780) {
            float tq = 6241.0f - 8.0f * (float)row;      // exact in fp32
            int i0 = (int)(0.5f * (79.0f - sqrtf(tq)));
            i0 = min(38, max(0, i0));
            int cum = 39 * i0 - ((i0 * (i0 - 1)) >> 1);
            if (cum > row) { --i0; cum = 39 * i0 - ((i0 * (i0 - 1)) >> 1); }
            else if (row - cum >= 39 - i0) { cum += 39 - i0; ++i0; }
            ii = i0; jj = i0 + 1 + (row - cum);
            addf = true;
        } else if (row >= 800 && row < 840) {
            ii = jj = row - 800;                          // node row
        }                                                 // else: dummy row
        unsigned short tmp[32];
#pragma unroll
        for (int q = 0; q < 8; q++) {
            int u = hf2 * 8 + q;
            float4 a = sh4[ii * 16 + (u ^ ((ii & 7) << 1))];
            if (addf) {
                float4 bq = sh4[jj * 16 + (u ^ ((jj & 7) << 1))];
                a.x += bq.x; a.y += bq.y; a.z += bq.z; a.w += bq.w;
            }
            tmp[4 * q + 0] = f2bf(a.x); tmp[4 * q + 1] = f2bf(a.y);
            tmp[4 * q + 2] = f2bf(a.z); tmp[4 * q + 3] = f2bf(a.w);
        }
        int r_sb = 32 * w + rl;
#pragma unroll
        for (int q = 0; q < 4; q++) {
            int cs = (hf2 * 4 + q) ^ (r_sb & 7);
            *(us8*)((char*)sB + r_sb * 128 + cs * 16) = *(const us8*)(tmp + 8 * q);
        }
    }

    // B-frag (activations) from LDS: node fixed, k = kt*32+rq*8+j contiguous
    auto ZB = [&](int nt, int kt) -> bf16x8 {
        int node = 32 * w + nt * 16 + nl;
        int cs = (kt * 4 + rq) ^ (node & 7);
        return __builtin_bit_cast(bf16x8,
            *(const us8*)((const char*)sB + node * 128 + cs * 16));
    };
    auto zstore = [&](int mt, int nt, const f32x4& v) {
        int node = 32 * w + nt * 16 + nl;
        int cs = (mt * 2 + (rq >> 1)) ^ (node & 7);
        uint2 u = make_uint2(pk2bf(v[0], v[1]), pk2bf(v[2], v[3]));
        *(uint2*)((char*)sB + node * 128 + cs * 16 + (rq & 1) * 8) = u;
    };

    // ---- GEMM1: Z1 = lrelu(E @ W0 + b0) -> sB (in place) ----
    {
        bf16x8 B[2][2];
#pragma unroll
        for (int nt = 0; nt < 2; nt++)
#pragma unroll
            for (int kt = 0; kt < 2; kt++) B[nt][kt] = ZB(nt, kt);
#pragma unroll
        for (int mt = 0; mt < 4; mt++) {
            float4 bv = cr.bv0[mt];
#pragma unroll
            for (int nt = 0; nt < 2; nt++) {
                f32x4 acc = (f32x4){0.f, 0.f, 0.f, 0.f};
                acc = __builtin_amdgcn_mfma_f32_16x16x32_bf16(cr.A1[mt][0], B[nt][0], acc, 0, 0, 0);
                acc = __builtin_amdgcn_mfma_f32_16x16x32_bf16(cr.A1[mt][1], B[nt][1], acc, 0, 0, 0);
                f32x4 z;
                z[0] = lrelu(acc[0] + bv.x); z[1] = lrelu(acc[1] + bv.y);
                z[2] = lrelu(acc[2] + bv.z); z[3] = lrelu(acc[3] + bv.w);
                zstore(mt, nt, z);
            }
        }
    }

    // ---- GEMM2: Z2 = lrelu(Z1 @ W1 + b1) -> sB (in place) ----
    {
        bf16x8 B[2][2];
#pragma unroll
        for (int nt = 0; nt < 2; nt++)
#pragma unroll
            for (int kt = 0; kt < 2; kt++) B[nt][kt] = ZB(nt, kt);
#pragma unroll
        for (int mt = 0; mt < 4; mt++) {
            float4 bv = cr.bv1[mt];
#pragma unroll
            for (int nt = 0; nt < 2; nt++) {
                f32x4 acc = (f32x4){0.f, 0.f, 0.f, 0.f};
                acc = __builtin_amdgcn_mfma_f32_16x16x32_bf16(cr.A2[mt][0], B[nt][0], acc, 0, 0, 0);
                acc = __builtin_amdgcn_mfma_f32_16x16x32_bf16(cr.A2[mt][1], B[nt][1], acc, 0, 0, 0);
                f32x4 z;
                z[0] = lrelu(acc[0] + bv.x); z[1] = lrelu(acc[1] + bv.y);
                z[2] = lrelu(acc[2] + bv.z); z[3] = lrelu(acc[3] + bv.w);
                zstore(mt, nt, z);
            }
        }
    }

    // ---- GEMM3: EP = Z2 @ W2 + b2 -> sEP (f32, stride 10 floats) ----
    {
        bf16x8 B[2][2];
#pragma unroll
        for (int nt = 0; nt < 2; nt++)
#pragma unroll
            for (int kt = 0; kt < 2; kt++) B[nt][kt] = ZB(nt, kt);
#pragma unroll
        for (int nt = 0; nt < 2; nt++) {
            f32x4 acc = (f32x4){0.f, 0.f, 0.f, 0.f};
            acc = __builtin_amdgcn_mfma_f32_16x16x32_bf16(cr.A3[0], B[nt][0], acc, 0, 0, 0);
            acc = __builtin_amdgcn_mfma_f32_16x16x32_bf16(cr.A3[1], B[nt][1], acc, 0, 0, 0);
            int rowe = R0 + nt * 16 + nl;
            bool valid = (rowe < 780) || (rowe >= 800 && rowe < 840);
            if (valid && rq < 3) {
                int epr = (rowe < 780) ? rowe : rowe - 20;   // nodes -> 780..819
                float* p = sEP + epr * 10 + rq * 4;
                *(float2*)p = make_float2(acc[0] + cr.bz[0], acc[1] + cr.bz[1]);
                if (rq < 2)
                    *(float2*)(p + 2) = make_float2(acc[2] + cr.bz[2], acc[3] + cr.bz[3]);
            }
        }
    }
}

__global__ __launch_bounds__(256) void k_mlp(const float* __restrict__ h,
                                             const unsigned short* __restrict__ wp,
                                             const float* __restrict__ be0,
                                             const float* __restrict__ be1,
                                             const float* __restrict__ be2,
                                             const float* __restrict__ bn0,
                                             const float* __restrict__ bn1,
                                             const float* __restrict__ bn2,
                                             float* __restrict__ X) {
    __shared__ __align__(16) float sh[N_NODES * 64];          // 10.25 KB, swizzled
    __shared__ __align__(16) unsigned short sB[128 * 64];     // 16 KB GEMM ping
    __shared__ __align__(8)  float sEP[820 * 10];             // 32.8 KB results

    const int tid = threadIdx.x;
    const int l = tid & 63;
    const int w = tid >> 6;
    const int g = blockIdx.x;
    const int rq = (l >> 4) & 3;

    float4* sh4 = (float4*)sh;

    // ---- load h for this graph: coalesced, swizzled ----
    {
        const float4* hg4 = (const float4*)(h + g * (N_NODES * 64));
#pragma unroll
        for (int k = 0; k < 3; k++) {
            int v = k * 256 + tid;
            if (v < 640) {
                int i = v >> 4, u = v & 15;
                sh4[i * 16 + (u ^ ((i & 7) << 1))] = hg4[v];
            }
        }
    }

    // A-frag loader (weights) from global, layout per k_prep
    auto WA = [&](const unsigned short* base, int mt, int kt) -> bf16x8 {
        return __builtin_bit_cast(bf16x8,
            *(const us8*)(base + ((mt * 2 + kt) * 64 + l) * 8));
    };

    // ---- hoist EDGE weights + biases to registers (chunk-invariant) ----
    ChunkRegs ce;
#pragma unroll
    for (int mt = 0; mt < 4; mt++) {
#pragma unroll
        for (int kt = 0; kt < 2; kt++) {
            ce.A1[mt][kt] = WA(wp, mt, kt);
            ce.A2[mt][kt] = WA(wp + 4096, mt, kt);
        }
        ce.bv0[mt] = *(const float4*)(be0 + mt * 16 + rq * 4);
        ce.bv1[mt] = *(const float4*)(be1 + mt * 16 + rq * 4);
    }
    ce.A3[0] = WA(wp + 8192, 0, 0);
    ce.A3[1] = WA(wp + 8192, 0, 1);
#pragma unroll
    for (int k = 0; k < 4; k++) {
        int f = rq * 4 + k;
        ce.bz[k] = (f < 10) ? be2[f] : 0.f;
    }

    __syncthreads();   // sh ready

    // ---- chunk loop: wave-local, no barriers ----
    for (int c = w; c < 27; c += 4) {
        if (c < 25) {
            run_chunk(c * 32, w, l, sh4, sB, sEP, ce);
        } else {
            // node chunks (25,26): load node weight set
            const unsigned short* wn = wp + PACK_PER_MLP;
            ChunkRegs cn;
#pragma unroll
            for (int mt = 0; mt < 4; mt++) {
#pragma unroll
                for (int kt = 0; kt < 2; kt++) {
                    cn.A1[mt][kt] = WA(wn, mt, kt);
                    cn.A2[mt][kt] = WA(wn + 4096, mt, kt);
                }
                cn.bv0[mt] = *(const float4*)(bn0 + mt * 16 + rq * 4);
                cn.bv1[mt] = *(const float4*)(bn1 + mt * 16 + rq * 4);
            }
            cn.A3[0] = WA(wn + 8192, 0, 0);
            cn.A3[1] = WA(wn + 8192, 0, 1);
#pragma unroll
            for (int k = 0; k < 4; k++) {
                int f = rq * 4 + k;
                cn.bz[k] = (f < 10) ? bn2[f] : 0.f;
            }
            run_chunk(c * 32, w, l, sh4, sB, sEP, cn);
        }
    }

    __syncthreads();   // all EP rows ready

    // ---- X sweep: thread owns whole 4x4 blocks; coalesced stores ----
    float* Xg = X + g * X_PER_G;
#pragma unroll
    for (int k = 0; k < 7; k++) {
        int b = k * 256 + tid;
        if (b < 1600) {
            int bi = b / 40;
            int bj = b - bi * 40;
            int ridx;
            if (bi == bj) {
                ridx = 780 + bi;
            } else {
                int mn = min(bi, bj), mx = max(bi, bj);
                ridx = 39 * mn - ((mn * (mn - 1)) >> 1) + (mx - mn - 1);
            }
            const float* ep = sEP + ridx * 10;
            float2 e0 = *(const float2*)(ep + 0);
            float2 e1 = *(const float2*)(ep + 2);
            float2 e2 = *(const float2*)(ep + 4);
            float2 e3 = *(const float2*)(ep + 6);
            float2 e4 = *(const float2*)(ep + 8);
            float f0 = e0.x, f1 = e0.y, f2 = e1.x, f3 = e1.y;
            float f4 = e2.x, f5 = e2.y, f6 = e3.x, f7 = e3.y;
            float f8 = e4.x, f9 = e4.y;
            float4 r0 = make_float4(f0, f1, f2, f3);
            float4 r1 = make_float4(f1, f4, f5, f6);
            float4 r2 = make_float4(f2, f5, f7, f8);
            float4 r3 = make_float4(f3, f6, f8, f9);
            float* p = Xg + (4 * bi) * X_STRIDE + 4 * bj;
            *(float4*)(p + 0 * X_STRIDE) = r0;
            *(float4*)(p + 1 * X_STRIDE) = r1;
            *(float4*)(p + 2 * X_STRIDE) = r2;
            *(float4*)(p + 3 * X_STRIDE) = r3;
        }
    }
}

// ---------------------------------------------------------------------------
// Launch
// ---------------------------------------------------------------------------
extern "C" void kernel_launch(void* const* d_in, const int* in_sizes, int n_in,
                              void* d_out, int out_size, void* d_ws, size_t ws_size,
                              hipStream_t stream) {
    const float* x   = (const float*)d_in[0];
    const float* Wg0 = (const float*)d_in[4];
    const float* bg0 = (const float*)d_in[5];
    const float* Wg1 = (const float*)d_in[6];
    const float* bg1 = (const float*)d_in[7];
    const float* Wg2 = (const float*)d_in[8];
    const float* bg2 = (const float*)d_in[9];
    const float* Wn0 = (const float*)d_in[10];
    const float* bn0 = (const float*)d_in[11];
    const float* Wn1 = (const float*)d_in[12];
    const float* bn1 = (const float*)d_in[13];
    const float* Wn2 = (const float*)d_in[14];
    const float* bn2 = (const float*)d_in[15];
    const float* We0 = (const float*)d_in[16];
    const float* be0 = (const float*)d_in[17];
    const float* We1 = (const float*)d_in[18];
    const float* be1 = (const float*)d_in[19];
    const float* We2 = (const float*)d_in[20];
    const float* be2 = (const float*)d_in[21];

    float* hout = (float*)d_out;            // h: 40960 x 64 fp32
    float* X    = hout + H_ELEMS;           // X: 1024 x 160 x 160 fp32
    unsigned short* wp = (unsigned short*)d_ws;  // 18432 bf16 packed weights

    k_prep<<<72, 256, 0, stream>>>(We0, We1, We2, Wn0, Wn1, Wn2, wp);
    k_gcn<<<G_GRAPHS, 256, 0, stream>>>(x, Wg0, bg0, Wg1, bg1, Wg2, bg2, hout);
    k_mlp<<<G_GRAPHS, 256, 0, stream>>>(hout, wp,
                                        be0, be1, be2,
                                        bn0, bn1, bn2, X);
}